// Round 13
// baseline (141.392 us; speedup 1.0000x reference)
//
#include <hip/hip_runtime.h>
#include <stdint.h>

// ---------------------------------------------------------------------------
// SelfAttentiveBimodalFusion: MLP(192->16->16) -> Q(8),K(8),V(64) -> full
// N x N attention -> out (N,64).  N = 12288.  fp32 in / fp32 out.
// Validated r5-r12: absmax 9.8e-4 vs thr 2.7e-3.
//
// r12 lesson: 64q/wave halves issue cost but 768 blocks -> occupancy 22%
// (3 blocks/CU cap) — gain cancelled by latency exposure.  r13 = r12's
// issue-efficient k2 with S=32 key-splits -> 1536 blocks (6/CU cap,
// 24 waves/CU), tiles=12.  po 48 MB bf16 (ws is 256 MiB).  k1 reverted to
// the exact r9/r10-validated version (r12's k1 rewrite coincided with +8us).
// ---------------------------------------------------------------------------

#define NN 12288

typedef float    f32x16 __attribute__((ext_vector_type(16)));
typedef short    s16x8  __attribute__((ext_vector_type(8)));
typedef unsigned short u16;

#define MFMA_32x32x16_BF16 __builtin_amdgcn_mfma_f32_32x32x16_bf16

// ws layout (bytes)
#define OFF_QB   0u          // N*8*2   = 196608  (bf16, pre-scaled)
#define OFF_KB   196608u     // N*8*2   = 196608  (bf16)
#define OFF_VT   393216u     // 384 tiles * 4608 B = 1769472 (bf16 V, tiled)
#define OFF_PO   2162688u    // S*N*64*2 bf16 O partials; pl follows (S*N*4 fp32)

typedef __attribute__((address_space(3))) void lds_void_t;
typedef const __attribute__((address_space(1))) void gbl_void_t;
__device__ __forceinline__ void gld16(const void* g, void* l) {
    __builtin_amdgcn_global_load_lds((gbl_void_t*)g, (lds_void_t*)l, 16, 0, 0);
}

__device__ __forceinline__ float bf2f(u16 s) {
    union { unsigned int u; float f; } c; c.u = ((unsigned int)s) << 16; return c.f;
}
__device__ __forceinline__ u16 f2bf(float f) {
    union { float f; unsigned int u; } c; c.f = f;
    return (u16)((c.u + 0x8000u) >> 16);
}
__device__ __forceinline__ unsigned int pk2(float a, float b) {
    union { float f; unsigned int u; } ca, cb; ca.f = a; cb.f = b;
    return ((ca.u + 0x8000u) >> 16) | ((cb.u + 0x8000u) & 0xffff0000u);
}
__device__ __forceinline__ unsigned int pkbf(float a, float b) {
#if __has_builtin(__builtin_amdgcn_cvt_pk_bf16_f32)
    auto r = __builtin_amdgcn_cvt_pk_bf16_f32(a, b);
    union { decltype(r) v; unsigned int u; } c; c.v = r; return c.u;
#else
    return pk2(a, b);
#endif
}
__device__ __forceinline__ f32x16 zf16() {
    f32x16 z;
#pragma unroll
    for (int i = 0; i < 16; ++i) z[i] = 0.f;
    return z;
}
__device__ __forceinline__ s16x8 zs8() {
    s16x8 z;
#pragma unroll
    for (int i = 0; i < 8; ++i) z[i] = 0;
    return z;
}

union U8 { s16x8 v; unsigned int u[4]; };

// ---------------- kernel 1: detect + weights->LDS + MLP -> Qb, Kb, Vt -------
// 192 blocks x 256 threads: 64 rows/block, 4 lanes per row. (r9/r10-validated)
__global__ __launch_bounds__(256) void k1_qkv(
    const void* __restrict__ xmain, const void* __restrict__ xmod,
    const void* __restrict__ we1, const void* __restrict__ we2,
    const void* __restrict__ wqp, const void* __restrict__ wkp,
    const void* __restrict__ wvp,
    u16* __restrict__ qb, u16* __restrict__ kb, u16* __restrict__ vt)
{
    __shared__ float wf[4608];
    __shared__ int   sflag;
    __shared__ float lh1[64][4][17];
    __shared__ float lh2[64][17];

    const int t = threadIdx.x;
    const int r = t >> 2;
    const int p = t & 3;
    const int row = blockIdx.x * 64 + r;

    if (t == 0) sflag = 0;
    __syncthreads();
    {
        float v = bf2f(((const u16*)xmod)[2 * t]);
        if (fabsf(v) > 16.f) atomicAdd(&sflag, 1);
    }
    __syncthreads();
    const int isf32 = (sflag > 8);

    const float SCL = 0.51006979f;       // (1/sqrt(8)) * log2(e)
    if (isf32) {
        const float* a1 = (const float*)we1; const float* a2 = (const float*)we2;
        const float* aq = (const float*)wqp; const float* ak = (const float*)wkp;
        const float* av = (const float*)wvp;
        for (int i = t; i < 4608; i += 256) {
            if      (i < 3072) wf[i] = a1[i];
            else if (i < 3328) wf[i] = a2[i - 3072];
            else if (i < 3456) wf[i] = aq[i - 3328] * SCL;
            else if (i < 3584) wf[i] = ak[i - 3456];
            else               wf[i] = av[i - 3584];
        }
    } else {
        const u16* a1 = (const u16*)we1; const u16* a2 = (const u16*)we2;
        const u16* aq = (const u16*)wqp; const u16* ak = (const u16*)wkp;
        const u16* av = (const u16*)wvp;
        for (int i = t; i < 4608; i += 256) {
            if      (i < 3072) wf[i] = bf2f(a1[i]);
            else if (i < 3328) wf[i] = bf2f(a2[i - 3072]);
            else if (i < 3456) wf[i] = bf2f(aq[i - 3328]) * SCL;
            else if (i < 3584) wf[i] = bf2f(ak[i - 3456]);
            else               wf[i] = bf2f(av[i - 3584]);
        }
    }
    __syncthreads();

    const float* __restrict__ W1 = wf;
    const float* __restrict__ W2 = wf + 3072;
    const float* __restrict__ Wq = wf + 3328;
    const float* __restrict__ Wk = wf + 3456;
    const float* __restrict__ Wv = wf + 3584;

    float h1p[16];
#pragma unroll
    for (int o = 0; o < 16; ++o) h1p[o] = 0.f;

    if (isf32) {
#pragma unroll
        for (int cc = 0; cc < 12; ++cc) {
            const int c = p + cc * 4;
            float4 xv = (c < 16)
                ? ((const float4*)xmain)[(size_t)row * 16 + c]
                : ((const float4*)xmod)[(size_t)row * 32 + (c - 16)];
            float xs[4] = {xv.x, xv.y, xv.z, xv.w};
#pragma unroll
            for (int j = 0; j < 4; ++j) {
                const float* wr = W1 + (c * 4 + j) * 16;
#pragma unroll
                for (int o = 0; o < 16; ++o) h1p[o] += xs[j] * wr[o];
            }
        }
    } else {
#pragma unroll
        for (int cc = 0; cc < 12; ++cc) {
            const int c = p + cc * 4;
            uint2 xv = (c < 16)
                ? ((const uint2*)xmain)[(size_t)row * 16 + c]
                : ((const uint2*)xmod)[(size_t)row * 32 + (c - 16)];
            float xs[4] = { bf2f((u16)(xv.x & 0xffff)), bf2f((u16)(xv.x >> 16)),
                            bf2f((u16)(xv.y & 0xffff)), bf2f((u16)(xv.y >> 16)) };
#pragma unroll
            for (int j = 0; j < 4; ++j) {
                const float* wr = W1 + (c * 4 + j) * 16;
#pragma unroll
                for (int o = 0; o < 16; ++o) h1p[o] += xs[j] * wr[o];
            }
        }
    }
#pragma unroll
    for (int o = 0; o < 16; ++o) lh1[r][p][o] = h1p[o];
    __syncthreads();

    float h1[16];
#pragma unroll
    for (int o = 0; o < 16; ++o)
        h1[o] = fmaxf(lh1[r][0][o] + lh1[r][1][o] + lh1[r][2][o] + lh1[r][3][o], 0.f);

#pragma unroll
    for (int oo = 0; oo < 4; ++oo) {
        const int o = p * 4 + oo;
        float s = 0.f;
#pragma unroll
        for (int j = 0; j < 16; ++j) s += h1[j] * W2[j * 16 + o];
        lh2[r][o] = fmaxf(s, 0.f);
    }
    __syncthreads();

    float h2[16];
#pragma unroll
    for (int j = 0; j < 16; ++j) h2[j] = lh2[r][j];

    {
        float q0 = 0.f, q1 = 0.f, k0 = 0.f, k1 = 0.f;
        const int o = 2 * p;
#pragma unroll
        for (int j = 0; j < 16; ++j) {
            q0 += h2[j] * Wq[j * 8 + o];
            q1 += h2[j] * Wq[j * 8 + o + 1];
            k0 += h2[j] * Wk[j * 8 + o];
            k1 += h2[j] * Wk[j * 8 + o + 1];
        }
        ((unsigned int*)qb)[(size_t)row * 4 + p] = pk2(q0, q1);
        ((unsigned int*)kb)[(size_t)row * 4 + p] = pk2(k0, k1);
    }

    // V store, key-tiled layout: [tile][c][kk], row stride 36 u16 (72 B)
    const int tI = row >> 5, kk = row & 31;
#pragma unroll
    for (int c16 = 0; c16 < 16; ++c16) {
        const int c = p * 16 + c16;
        float v = 0.f;
#pragma unroll
        for (int j = 0; j < 16; ++j) v += h2[j] * Wv[j * 64 + c];
        vt[(size_t)tI * 2304 + c * 36 + kk] = f2bf(v);
    }
}

// --------------------------- kernel 2: attention partials -------------------
// grid = 48 q-blocks * S key-splits (S=32 -> 1536 blocks, 6/CU); block =
// 256 queries (4 waves x 64q, 2 Q-frags/wave); shared DMA-staged V-tile
// double buffer (r10-validated sync structure).  bf16 partials out.
__global__ __launch_bounds__(256, 2) void k2_attn(
    const u16* __restrict__ qb, const u16* __restrict__ kb,
    const u16* __restrict__ vt,
    u16* __restrict__ po, float* __restrict__ pl,
    int nsplit, int tiles)
{
    __shared__ union SM {
        uint4 stage[2][288];                 // 9216 B V-tile double buffer
        float sf[2304];                      // epilogue transpose (aliased)
    } sm;

    const int tid  = threadIdx.x;
    const int lane = tid & 63;
    const int half = lane >> 5;
    const int l31  = lane & 31;
    const int w    = tid >> 6;               // wave 0..3
    const int qB   = (blockIdx.x % 48) * 256;
    const int sp   = blockIdx.x / 48;
    const int myq  = qB + 64 * w;            // this wave's first query
    const int key_start = sp * (NN / nsplit);
    const int t0 = key_start >> 5;

    const f32x16 Z = zf16();
    s16x8 qf0 = zs8(), qf1 = zs8();
    if (!half) {
        qf0 = *(const s16x8*)(qb + (size_t)(myq + l31) * 8);
        qf1 = *(const s16x8*)(qb + (size_t)(myq + 32 + l31) * 8);
    }

    f32x16 acc00 = Z, acc01 = Z, acc10 = Z, acc11 = Z;  // [frag][ct]
    float ls0 = 0.f, ls1 = 0.f;

    // DMA tile 0 -> stage[0]; wave w stages its quarter (1152 B)
    {
        const char* g = (const char*)vt + (size_t)t0 * 4608 + 1152 * w + lane * 16;
        char* l = (char*)&sm.stage[0][0] + 1152 * w;   // wave-uniform base
        gld16(g, l);
        if (lane < 8) gld16(g + 1024, l + 1024);
    }
    s16x8 ka_c = *(const s16x8*)(kb + (size_t)(key_start + l31) * 8);

    for (int kt = 0; kt < tiles; ++kt) {
        __builtin_amdgcn_s_waitcnt(0x0F70);  // vmcnt(0): my DMA + ka done
        __syncthreads();                     // all waves' DMA visible
        const int cb = kt & 1;
        const bool has_next = (kt + 1 < tiles);

        s16x8 ka_n;
        if (has_next) {
            ka_n = *(const s16x8*)(kb + (size_t)(key_start + (kt + 1) * 32 + l31) * 8);
            const char* g = (const char*)vt + (size_t)(t0 + kt + 1) * 4608
                          + 1152 * w + lane * 16;
            char* l = (char*)&sm.stage[cb ^ 1][0] + 1152 * w;
            gld16(g, l);
            if (lane < 8) gld16(g + 1024, l + 1024);
        }

        // V A-fragments (shared by both Q-frags; r5-validated relabeling)
        const u16* base = (const u16*)&sm.stage[cb][0];
        const u16* r0 = base + l31 * 36 + 4 * half;          // ct=0
        const u16* r1 = base + (32 + l31) * 36 + 4 * half;   // ct=1
        U8 vaA0, vaA1, vaB0, vaB1;           // (ks, ct)
        {
            uint2 x0, x1;
            x0 = *(const uint2*)(r0);       x1 = *(const uint2*)(r0 + 8);
            vaA0.u[0] = x0.x; vaA0.u[1] = x0.y; vaA0.u[2] = x1.x; vaA0.u[3] = x1.y;
            x0 = *(const uint2*)(r1);       x1 = *(const uint2*)(r1 + 8);
            vaA1.u[0] = x0.x; vaA1.u[1] = x0.y; vaA1.u[2] = x1.x; vaA1.u[3] = x1.y;
            x0 = *(const uint2*)(r0 + 16);  x1 = *(const uint2*)(r0 + 24);
            vaB0.u[0] = x0.x; vaB0.u[1] = x0.y; vaB0.u[2] = x1.x; vaB0.u[3] = x1.y;
            x0 = *(const uint2*)(r1 + 16);  x1 = *(const uint2*)(r1 + 24);
            vaB1.u[0] = x0.x; vaB1.u[1] = x0.y; vaB1.u[2] = x1.x; vaB1.u[3] = x1.y;
        }

        // ---- Q-frag 0 ----
        {
            f32x16 S = MFMA_32x32x16_BF16(ka_c, qf0, Z, 0, 0, 0);
            float pr[16];
            float a = 0.f, b = 0.f;
#pragma unroll
            for (int r = 0; r < 8; ++r) {
                pr[r]     = __builtin_amdgcn_exp2f(S[r]);
                pr[r + 8] = __builtin_amdgcn_exp2f(S[r + 8]);
                a += pr[r]; b += pr[r + 8];
            }
            ls0 += a + b;
            U8 pbA, pbB;
#pragma unroll
            for (int i = 0; i < 4; ++i) {
                pbA.u[i] = pkbf(pr[2 * i],     pr[2 * i + 1]);
                pbB.u[i] = pkbf(pr[8 + 2 * i], pr[8 + 2 * i + 1]);
            }
            acc00 = MFMA_32x32x16_BF16(vaA0.v, pbA.v, acc00, 0, 0, 0);
            acc01 = MFMA_32x32x16_BF16(vaA1.v, pbA.v, acc01, 0, 0, 0);
            acc00 = MFMA_32x32x16_BF16(vaB0.v, pbB.v, acc00, 0, 0, 0);
            acc01 = MFMA_32x32x16_BF16(vaB1.v, pbB.v, acc01, 0, 0, 0);
        }
        // ---- Q-frag 1 ----
        {
            f32x16 S = MFMA_32x32x16_BF16(ka_c, qf1, Z, 0, 0, 0);
            float pr[16];
            float a = 0.f, b = 0.f;
#pragma unroll
            for (int r = 0; r < 8; ++r) {
                pr[r]     = __builtin_amdgcn_exp2f(S[r]);
                pr[r + 8] = __builtin_amdgcn_exp2f(S[r + 8]);
                a += pr[r]; b += pr[r + 8];
            }
            ls1 += a + b;
            U8 pbA, pbB;
#pragma unroll
            for (int i = 0; i < 4; ++i) {
                pbA.u[i] = pkbf(pr[2 * i],     pr[2 * i + 1]);
                pbB.u[i] = pkbf(pr[8 + 2 * i], pr[8 + 2 * i + 1]);
            }
            acc10 = MFMA_32x32x16_BF16(vaA0.v, pbA.v, acc10, 0, 0, 0);
            acc11 = MFMA_32x32x16_BF16(vaA1.v, pbA.v, acc11, 0, 0, 0);
            acc10 = MFMA_32x32x16_BF16(vaB0.v, pbB.v, acc10, 0, 0, 0);
            acc11 = MFMA_32x32x16_BF16(vaB1.v, pbB.v, acc11, 0, 0, 0);
        }

        if (has_next) ka_c = ka_n;
    }

    // lanes l and l+32 hold complementary key-halves of query l31's sum
    ls0 += __shfl_xor(ls0, 32, 64);
    ls1 += __shfl_xor(ls1, 32, 64);

    // ---- epilogue: 8 rounds (wave j>>1, frag j&1) via aliased staging LDS --
    u16* poS = po + (size_t)sp * (NN * 64);
    for (int j = 0; j < 8; ++j) {
        __syncthreads();
        if (w == (j >> 1)) {
            const int f = j & 1;
#pragma unroll
            for (int r = 0; r < 16; ++r) {
                const int c = (r & 3) + 8 * (r >> 2) + 4 * half;
                sm.sf[c * 33 + l31]        = f ? acc10[r] : acc00[r];
                sm.sf[(32 + c) * 33 + l31] = f ? acc11[r] : acc01[r];
            }
            if (lane < 32) sm.sf[2112 + l31] = f ? ls1 : ls0;
        }
        __syncthreads();
        const int rq = tid >> 3;             // query 0..31
        const int c0 = (tid & 7) * 8;        // channel base
        unsigned int u0 = pkbf(sm.sf[(c0 + 0) * 33 + rq], sm.sf[(c0 + 1) * 33 + rq]);
        unsigned int u1 = pkbf(sm.sf[(c0 + 2) * 33 + rq], sm.sf[(c0 + 3) * 33 + rq]);
        unsigned int u2 = pkbf(sm.sf[(c0 + 4) * 33 + rq], sm.sf[(c0 + 5) * 33 + rq]);
        unsigned int u3 = pkbf(sm.sf[(c0 + 6) * 33 + rq], sm.sf[(c0 + 7) * 33 + rq]);
        *(uint4*)(poS + (size_t)(qB + 32 * j + rq) * 64 + c0) =
            make_uint4(u0, u1, u2, u3);
        if (tid < 32)
            pl[(size_t)sp * NN + qB + 32 * j + tid] = sm.sf[2112 + tid];
    }
}

// --------------------------- kernel 3: reduce splits + normalize ------------
__global__ __launch_bounds__(256) void k3_norm(
    const u16* __restrict__ po, const float* __restrict__ pl,
    float4* __restrict__ out, int nsplit)
{
    const int i = blockIdx.x * 256 + threadIdx.x;   // 196608 float4 outputs
    const int row = i >> 4;
    const int c0 = (i & 15) * 4;
    float l = 0.f;
    float o0 = 0.f, o1 = 0.f, o2 = 0.f, o3 = 0.f;
    for (int s = 0; s < nsplit; ++s) {
        l += pl[(size_t)s * NN + row];
        uint2 p = *(const uint2*)(po + (size_t)s * (NN * 64) +
                                  (size_t)row * 64 + c0);
        o0 += bf2f((u16)(p.x & 0xffff)); o1 += bf2f((u16)(p.x >> 16));
        o2 += bf2f((u16)(p.y & 0xffff)); o3 += bf2f((u16)(p.y >> 16));
    }
    const float rl = 1.0f / l;
    out[i] = make_float4(o0 * rl, o1 * rl, o2 * rl, o3 * rl);
}

// ---------------------------------------------------------------------------
extern "C" void kernel_launch(void* const* d_in, const int* in_sizes, int n_in,
                              void* d_out, int out_size, void* d_ws, size_t ws_size,
                              hipStream_t stream)
{
    const void* xmain = d_in[0];
    const void* xmod  = d_in[1];
    // d_in[2] = xyz (unused by the reference)
    const void* we1   = d_in[3];
    const void* we2   = d_in[4];
    const void* wq    = d_in[5];
    const void* wk    = d_in[6];
    const void* wv    = d_in[7];

    char* ws = (char*)d_ws;
    u16*   qb   = (u16*)  (ws + OFF_QB);
    u16*   kb   = (u16*)  (ws + OFF_KB);
    u16*   vt   = (u16*)  (ws + OFF_VT);

    // pick the largest key-split S whose partials fit in ws
    int S = 1;
    for (int cand = 32; cand >= 1; cand >>= 1) {
        size_t need = (size_t)OFF_PO + (size_t)cand * (NN * 64 * 2) +
                      (size_t)cand * (NN * 4);
        if (ws_size >= need) { S = cand; break; }
    }
    u16*   po = (u16*)(ws + OFF_PO);
    float* pl = (float*)(ws + OFF_PO + (size_t)S * (NN * 64 * 2));
    const int tiles = NN / (32 * S);

    k1_qkv<<<192, 256, 0, stream>>>(xmain, xmod, we1, we2, wq, wk, wv,
                                    qb, kb, vt);
    k2_attn<<<48 * S, 256, 0, stream>>>(qb, kb, vt, po, pl, S, tiles);
    k3_norm<<<768, 256, 0, stream>>>(po, pl, (float4*)d_out, S);
}

// Round 14
// 132.272 us; speedup vs baseline: 1.0690x; 1.0690x over previous
//
#include <hip/hip_runtime.h>
#include <stdint.h>

// ---------------------------------------------------------------------------
// SelfAttentiveBimodalFusion: MLP(192->16->16) -> Q(8),K(8),V(64) -> full
// N x N attention -> out (N,64).  N = 12288.  fp32 in / fp32 out.
// Validated r5-r13: absmax 9.8e-4 vs thr 2.7e-3.
//
// r13 lesson: the ~45-us k2 wall is (a) AGPR-driven occupancy (64-AGPR acc
// of the 2-frag wave -> ~140 unified regs -> 3 waves/SIMD; VGPR_Count hides
// AGPRs) and (b) per-tile vmcnt(0)+barrier serialization (24 rounds/block).
// r14: 32q/wave (32 AGPR, ~100 total regs -> 5-6 waves/SIMD), S=16
// (1536 blocks, 6/CU), TWO key-tiles per barrier round (12 rounds/block),
// 4-slot LDS staging ring, pointer-increment addressing.
// Fragment/relabel algebra byte-identical to the r5-validated kernel.
// ---------------------------------------------------------------------------

#define NN 12288

typedef float    f32x16 __attribute__((ext_vector_type(16)));
typedef short    s16x8  __attribute__((ext_vector_type(8)));
typedef unsigned short u16;

#define MFMA_32x32x16_BF16 __builtin_amdgcn_mfma_f32_32x32x16_bf16

// ws layout (bytes)
#define OFF_QB   0u          // N*8*2   = 196608  (bf16, pre-scaled)
#define OFF_KB   196608u     // N*8*2   = 196608  (bf16)
#define OFF_VT   393216u     // 384 tiles * 4608 B = 1769472 (bf16 V, tiled)
#define OFF_PO   2162688u    // S*N*64*2 bf16 O partials; pl follows (S*N*4 fp32)

typedef __attribute__((address_space(3))) void lds_void_t;
typedef const __attribute__((address_space(1))) void gbl_void_t;
__device__ __forceinline__ void gld16(const void* g, void* l) {
    __builtin_amdgcn_global_load_lds((gbl_void_t*)g, (lds_void_t*)l, 16, 0, 0);
}

__device__ __forceinline__ float bf2f(u16 s) {
    union { unsigned int u; float f; } c; c.u = ((unsigned int)s) << 16; return c.f;
}
__device__ __forceinline__ u16 f2bf(float f) {
    union { float f; unsigned int u; } c; c.f = f;
    return (u16)((c.u + 0x8000u) >> 16);
}
__device__ __forceinline__ unsigned int pk2(float a, float b) {
    union { float f; unsigned int u; } ca, cb; ca.f = a; cb.f = b;
    return ((ca.u + 0x8000u) >> 16) | ((cb.u + 0x8000u) & 0xffff0000u);
}
__device__ __forceinline__ unsigned int pkbf(float a, float b) {
#if __has_builtin(__builtin_amdgcn_cvt_pk_bf16_f32)
    auto r = __builtin_amdgcn_cvt_pk_bf16_f32(a, b);
    union { decltype(r) v; unsigned int u; } c; c.v = r; return c.u;
#else
    return pk2(a, b);
#endif
}
__device__ __forceinline__ f32x16 zf16() {
    f32x16 z;
#pragma unroll
    for (int i = 0; i < 16; ++i) z[i] = 0.f;
    return z;
}
__device__ __forceinline__ s16x8 zs8() {
    s16x8 z;
#pragma unroll
    for (int i = 0; i < 8; ++i) z[i] = 0;
    return z;
}

union U8 { s16x8 v; unsigned int u[4]; };

// ---------------- kernel 1: detect + weights->LDS + MLP -> Qb, Kb, Vt -------
// 192 blocks x 256 threads: 64 rows/block, 4 lanes per row. (r9/r10-validated)
__global__ __launch_bounds__(256) void k1_qkv(
    const void* __restrict__ xmain, const void* __restrict__ xmod,
    const void* __restrict__ we1, const void* __restrict__ we2,
    const void* __restrict__ wqp, const void* __restrict__ wkp,
    const void* __restrict__ wvp,
    u16* __restrict__ qb, u16* __restrict__ kb, u16* __restrict__ vt)
{
    __shared__ float wf[4608];
    __shared__ int   sflag;
    __shared__ float lh1[64][4][17];
    __shared__ float lh2[64][17];

    const int t = threadIdx.x;
    const int r = t >> 2;
    const int p = t & 3;
    const int row = blockIdx.x * 64 + r;

    if (t == 0) sflag = 0;
    __syncthreads();
    {
        float v = bf2f(((const u16*)xmod)[2 * t]);
        if (fabsf(v) > 16.f) atomicAdd(&sflag, 1);
    }
    __syncthreads();
    const int isf32 = (sflag > 8);

    const float SCL = 0.51006979f;       // (1/sqrt(8)) * log2(e)
    if (isf32) {
        const float* a1 = (const float*)we1; const float* a2 = (const float*)we2;
        const float* aq = (const float*)wqp; const float* ak = (const float*)wkp;
        const float* av = (const float*)wvp;
        for (int i = t; i < 4608; i += 256) {
            if      (i < 3072) wf[i] = a1[i];
            else if (i < 3328) wf[i] = a2[i - 3072];
            else if (i < 3456) wf[i] = aq[i - 3328] * SCL;
            else if (i < 3584) wf[i] = ak[i - 3456];
            else               wf[i] = av[i - 3584];
        }
    } else {
        const u16* a1 = (const u16*)we1; const u16* a2 = (const u16*)we2;
        const u16* aq = (const u16*)wqp; const u16* ak = (const u16*)wkp;
        const u16* av = (const u16*)wvp;
        for (int i = t; i < 4608; i += 256) {
            if      (i < 3072) wf[i] = bf2f(a1[i]);
            else if (i < 3328) wf[i] = bf2f(a2[i - 3072]);
            else if (i < 3456) wf[i] = bf2f(aq[i - 3328]) * SCL;
            else if (i < 3584) wf[i] = bf2f(ak[i - 3456]);
            else               wf[i] = bf2f(av[i - 3584]);
        }
    }
    __syncthreads();

    const float* __restrict__ W1 = wf;
    const float* __restrict__ W2 = wf + 3072;
    const float* __restrict__ Wq = wf + 3328;
    const float* __restrict__ Wk = wf + 3456;
    const float* __restrict__ Wv = wf + 3584;

    float h1p[16];
#pragma unroll
    for (int o = 0; o < 16; ++o) h1p[o] = 0.f;

    if (isf32) {
#pragma unroll
        for (int cc = 0; cc < 12; ++cc) {
            const int c = p + cc * 4;
            float4 xv = (c < 16)
                ? ((const float4*)xmain)[(size_t)row * 16 + c]
                : ((const float4*)xmod)[(size_t)row * 32 + (c - 16)];
            float xs[4] = {xv.x, xv.y, xv.z, xv.w};
#pragma unroll
            for (int j = 0; j < 4; ++j) {
                const float* wr = W1 + (c * 4 + j) * 16;
#pragma unroll
                for (int o = 0; o < 16; ++o) h1p[o] += xs[j] * wr[o];
            }
        }
    } else {
#pragma unroll
        for (int cc = 0; cc < 12; ++cc) {
            const int c = p + cc * 4;
            uint2 xv = (c < 16)
                ? ((const uint2*)xmain)[(size_t)row * 16 + c]
                : ((const uint2*)xmod)[(size_t)row * 32 + (c - 16)];
            float xs[4] = { bf2f((u16)(xv.x & 0xffff)), bf2f((u16)(xv.x >> 16)),
                            bf2f((u16)(xv.y & 0xffff)), bf2f((u16)(xv.y >> 16)) };
#pragma unroll
            for (int j = 0; j < 4; ++j) {
                const float* wr = W1 + (c * 4 + j) * 16;
#pragma unroll
                for (int o = 0; o < 16; ++o) h1p[o] += xs[j] * wr[o];
            }
        }
    }
#pragma unroll
    for (int o = 0; o < 16; ++o) lh1[r][p][o] = h1p[o];
    __syncthreads();

    float h1[16];
#pragma unroll
    for (int o = 0; o < 16; ++o)
        h1[o] = fmaxf(lh1[r][0][o] + lh1[r][1][o] + lh1[r][2][o] + lh1[r][3][o], 0.f);

#pragma unroll
    for (int oo = 0; oo < 4; ++oo) {
        const int o = p * 4 + oo;
        float s = 0.f;
#pragma unroll
        for (int j = 0; j < 16; ++j) s += h1[j] * W2[j * 16 + o];
        lh2[r][o] = fmaxf(s, 0.f);
    }
    __syncthreads();

    float h2[16];
#pragma unroll
    for (int j = 0; j < 16; ++j) h2[j] = lh2[r][j];

    {
        float q0 = 0.f, q1 = 0.f, k0 = 0.f, k1 = 0.f;
        const int o = 2 * p;
#pragma unroll
        for (int j = 0; j < 16; ++j) {
            q0 += h2[j] * Wq[j * 8 + o];
            q1 += h2[j] * Wq[j * 8 + o + 1];
            k0 += h2[j] * Wk[j * 8 + o];
            k1 += h2[j] * Wk[j * 8 + o + 1];
        }
        ((unsigned int*)qb)[(size_t)row * 4 + p] = pk2(q0, q1);
        ((unsigned int*)kb)[(size_t)row * 4 + p] = pk2(k0, k1);
    }

    // V store, key-tiled layout: [tile][c][kk], row stride 36 u16 (72 B)
    const int tI = row >> 5, kk = row & 31;
#pragma unroll
    for (int c16 = 0; c16 < 16; ++c16) {
        const int c = p * 16 + c16;
        float v = 0.f;
#pragma unroll
        for (int j = 0; j < 16; ++j) v += h2[j] * Wv[j * 64 + c];
        vt[(size_t)tI * 2304 + c * 36 + kk] = f2bf(v);
    }
}

// --------------------------- kernel 2: attention partials -------------------
// grid = 96 q-blocks * S key-splits (S=16 -> 1536 blocks); block = 128 q
// (4 waves x 32q, 32-AGPR acc).  TWO key-tiles per barrier round (rounds =
// NN/(64S) = 12): 4-slot shared LDS staging ring, DMA prefetch of the next
// round's pair while computing the current pair.  bf16 partials, no atomics.
__global__ __launch_bounds__(256, 4) void k2_attn(
    const u16* __restrict__ qb, const u16* __restrict__ kb,
    const u16* __restrict__ vt,
    u16* __restrict__ po, float* __restrict__ pl,
    int nsplit, int rounds)
{
    __shared__ union SM {
        uint4 stage[4][288];                 // 18432 B, 4 tile slots
        float sf[2304];                      // epilogue transpose (aliased)
    } sm;

    const int tid  = threadIdx.x;
    const int lane = tid & 63;
    const int half = lane >> 5;
    const int l31  = lane & 31;
    const int w    = tid >> 6;               // wave 0..3
    const int qB   = (blockIdx.x % 96) * 128;
    const int sp   = blockIdx.x / 96;
    const int myq  = qB + 32 * w;
    const int key_start = sp * (NN / nsplit);
    const int t0 = key_start >> 5;           // first V tile index

    const f32x16 Z = zf16();
    s16x8 qf = zs8();
    if (!half) qf = *(const s16x8*)(qb + (size_t)(myq + l31) * 8);

    f32x16 acc0 = Z, acc1 = Z;
    float ls = 0.f;

    // wave-local staging pointers (pointer-increment addressing)
    const char* gv = (const char*)vt + (size_t)t0 * 4608 + 1152 * w + lane * 16;
    const u16*  kp = kb + (size_t)(key_start + l31) * 8;   // +256 u16 per tile

#define STAGE(gp, slot)                                                       \
    do {                                                                      \
        char* l_ = (char*)&sm.stage[(slot)][0] + 1152 * w;                    \
        gld16((gp), l_);                                                      \
        if (lane < 8) gld16((gp) + 1024, l_ + 1024);                          \
    } while (0)

    // prologue: stage tiles 0,1 into slots 0,1; K for tiles 0,1
    STAGE(gv, 0);
    STAGE(gv + 4608, 1);
    s16x8 ka0 = *(const s16x8*)(kp);
    s16x8 ka1 = *(const s16x8*)(kp + 256);

    for (int r = 0; r < rounds; ++r) {
        __builtin_amdgcn_s_waitcnt(0x0F70);  // vmcnt(0): this round's DMA+K done
        __syncthreads();
        const int sA = (r & 1) * 2;          // slots for this round
        const bool has_next = (r + 1 < rounds);

        s16x8 kn0, kn1;
        if (has_next) {
            const u16* kpn = kp + (size_t)(2 * r + 2) * 256;
            kn0 = *(const s16x8*)(kpn);
            kn1 = *(const s16x8*)(kpn + 256);
            const char* gn = gv + (size_t)(2 * r + 2) * 4608;
            const int sN = ((r + 1) & 1) * 2;
            STAGE(gn, sN);
            STAGE(gn + 4608, sN + 1);
        }

        // ---- two subtiles: (ka0, slot sA) and (ka1, slot sA+1) ----
#pragma unroll
        for (int sub = 0; sub < 2; ++sub) {
            const s16x8 ka = sub ? ka1 : ka0;
            f32x16 S = MFMA_32x32x16_BF16(ka, qf, Z, 0, 0, 0);

            float pr[16];
            float a = 0.f, b = 0.f;
#pragma unroll
            for (int rr = 0; rr < 8; ++rr) {
                pr[rr]     = __builtin_amdgcn_exp2f(S[rr]);
                pr[rr + 8] = __builtin_amdgcn_exp2f(S[rr + 8]);
                a += pr[rr]; b += pr[rr + 8];
            }
            ls += a + b;

            U8 pbA, pbB;
#pragma unroll
            for (int i = 0; i < 4; ++i) {
                pbA.u[i] = pkbf(pr[2 * i],     pr[2 * i + 1]);
                pbB.u[i] = pkbf(pr[8 + 2 * i], pr[8 + 2 * i + 1]);
            }

            // A-fragments from LDS (r5-validated relabeling)
            const u16* base = (const u16*)&sm.stage[sA + sub][0];
            const u16* r0 = base + l31 * 36 + 4 * half;          // ct=0
            const u16* r1 = base + (32 + l31) * 36 + 4 * half;   // ct=1
            U8 va;
            uint2 x0, x1;
            x0 = *(const uint2*)(r0);       x1 = *(const uint2*)(r0 + 8);
            va.u[0] = x0.x; va.u[1] = x0.y; va.u[2] = x1.x; va.u[3] = x1.y;
            acc0 = MFMA_32x32x16_BF16(va.v, pbA.v, acc0, 0, 0, 0);
            x0 = *(const uint2*)(r1);       x1 = *(const uint2*)(r1 + 8);
            va.u[0] = x0.x; va.u[1] = x0.y; va.u[2] = x1.x; va.u[3] = x1.y;
            acc1 = MFMA_32x32x16_BF16(va.v, pbA.v, acc1, 0, 0, 0);
            x0 = *(const uint2*)(r0 + 16);  x1 = *(const uint2*)(r0 + 24);
            va.u[0] = x0.x; va.u[1] = x0.y; va.u[2] = x1.x; va.u[3] = x1.y;
            acc0 = MFMA_32x32x16_BF16(va.v, pbB.v, acc0, 0, 0, 0);
            x0 = *(const uint2*)(r1 + 16);  x1 = *(const uint2*)(r1 + 24);
            va.u[0] = x0.x; va.u[1] = x0.y; va.u[2] = x1.x; va.u[3] = x1.y;
            acc1 = MFMA_32x32x16_BF16(va.v, pbB.v, acc1, 0, 0, 0);
        }

        if (has_next) { ka0 = kn0; ka1 = kn1; }
    }
#undef STAGE

    // lanes l and l+32 hold complementary key-halves of query l31's sum
    ls += __shfl_xor(ls, 32, 64);

    // ---- epilogue: per-wave transpose through the (aliased) staging LDS ----
    u16* poS = po + (size_t)sp * (NN * 64);
    for (int j = 0; j < 4; ++j) {
        __syncthreads();
        if (w == j) {
#pragma unroll
            for (int r = 0; r < 16; ++r) {
                const int c = (r & 3) + 8 * (r >> 2) + 4 * half;
                sm.sf[c * 33 + l31]        = acc0[r];
                sm.sf[(32 + c) * 33 + l31] = acc1[r];
            }
            if (lane < 32) sm.sf[2112 + l31] = ls;
        }
        __syncthreads();
        const int rq = tid >> 3;             // query 0..31
        const int c0 = (tid & 7) * 8;        // channel base
        unsigned int u0 = pkbf(sm.sf[(c0 + 0) * 33 + rq], sm.sf[(c0 + 1) * 33 + rq]);
        unsigned int u1 = pkbf(sm.sf[(c0 + 2) * 33 + rq], sm.sf[(c0 + 3) * 33 + rq]);
        unsigned int u2 = pkbf(sm.sf[(c0 + 4) * 33 + rq], sm.sf[(c0 + 5) * 33 + rq]);
        unsigned int u3 = pkbf(sm.sf[(c0 + 6) * 33 + rq], sm.sf[(c0 + 7) * 33 + rq]);
        *(uint4*)(poS + (size_t)(qB + 32 * j + rq) * 64 + c0) =
            make_uint4(u0, u1, u2, u3);
        if (tid < 32)
            pl[(size_t)sp * NN + qB + 32 * j + tid] = sm.sf[2112 + tid];
    }
}

// --------------------------- kernel 3: reduce splits + normalize ------------
__global__ __launch_bounds__(256) void k3_norm(
    const u16* __restrict__ po, const float* __restrict__ pl,
    float4* __restrict__ out, int nsplit)
{
    const int i = blockIdx.x * 256 + threadIdx.x;   // 196608 float4 outputs
    const int row = i >> 4;
    const int c0 = (i & 15) * 4;
    float l = 0.f;
    float o0 = 0.f, o1 = 0.f, o2 = 0.f, o3 = 0.f;
    for (int s = 0; s < nsplit; ++s) {
        l += pl[(size_t)s * NN + row];
        uint2 p = *(const uint2*)(po + (size_t)s * (NN * 64) +
                                  (size_t)row * 64 + c0);
        o0 += bf2f((u16)(p.x & 0xffff)); o1 += bf2f((u16)(p.x >> 16));
        o2 += bf2f((u16)(p.y & 0xffff)); o3 += bf2f((u16)(p.y >> 16));
    }
    const float rl = 1.0f / l;
    out[i] = make_float4(o0 * rl, o1 * rl, o2 * rl, o3 * rl);
}

// ---------------------------------------------------------------------------
extern "C" void kernel_launch(void* const* d_in, const int* in_sizes, int n_in,
                              void* d_out, int out_size, void* d_ws, size_t ws_size,
                              hipStream_t stream)
{
    const void* xmain = d_in[0];
    const void* xmod  = d_in[1];
    // d_in[2] = xyz (unused by the reference)
    const void* we1   = d_in[3];
    const void* we2   = d_in[4];
    const void* wq    = d_in[5];
    const void* wk    = d_in[6];
    const void* wv    = d_in[7];

    char* ws = (char*)d_ws;
    u16*   qb   = (u16*)  (ws + OFF_QB);
    u16*   kb   = (u16*)  (ws + OFF_KB);
    u16*   vt   = (u16*)  (ws + OFF_VT);

    // pick the largest key-split S (<=16) whose partials fit in ws
    int S = 1;
    for (int cand = 16; cand >= 1; cand >>= 1) {
        size_t need = (size_t)OFF_PO + (size_t)cand * (NN * 64 * 2) +
                      (size_t)cand * (NN * 4);
        if (ws_size >= need) { S = cand; break; }
    }
    u16*   po = (u16*)(ws + OFF_PO);
    float* pl = (float*)(ws + OFF_PO + (size_t)S * (NN * 64 * 2));
    const int rounds = NN / (64 * S);

    k1_qkv<<<192, 256, 0, stream>>>(xmain, xmod, we1, we2, wq, wk, wv,
                                    qb, kb, vt);
    k2_attn<<<96 * S, 256, 0, stream>>>(qb, kb, vt, po, pl, S, rounds);
    k3_norm<<<768, 256, 0, stream>>>(po, pl, (float4*)d_out, S);
}